// Round 13
// baseline (75.625 us; speedup 1.0000x reference)
//
#include <hip/hip_runtime.h>
#include <hip/hip_bf16.h>
#include <math.h>

#define S_LEN 2048
#define E_DIM 1024
#define NHEAD 8
#define DH 128
#define E3 3072

typedef short bf16x8 __attribute__((ext_vector_type(8)));
typedef short bf16x4 __attribute__((ext_vector_type(4)));
typedef float f32x4 __attribute__((ext_vector_type(4)));
typedef float f32x16 __attribute__((ext_vector_type(16)));

#define MFMA3216(a,b,c) __builtin_amdgcn_mfma_f32_32x32x16_bf16(a,b,c,0,0,0)
#define Z16 {0.f,0.f,0.f,0.f,0.f,0.f,0.f,0.f,0.f,0.f,0.f,0.f,0.f,0.f,0.f,0.f}
#define CROW(r) (((r)&3) + 8*((r)>>2))

__device__ __forceinline__ unsigned short f2bf(float f){
  union{float f; unsigned u;} x; x.f = f;
  unsigned r = x.u + 0x7FFF + ((x.u>>16)&1);
  return (unsigned short)(r>>16);
}

__device__ __forceinline__ unsigned cvtpk(float lo, float hi){
  unsigned r;
  asm("v_cvt_pk_bf16_f32 %0, %1, %2" : "=v"(r) : "v"(lo), "v"(hi));
  return r;
}

__device__ __forceinline__ float logsigf(float x){
  return fminf(x, 0.f) - log1pf(expf(-fabsf(x)));
}

typedef const __attribute__((address_space(1))) unsigned int* gas1_t;
typedef __attribute__((address_space(3))) unsigned int* las3_t;
__device__ __forceinline__ void stage16(const ushort* g, ushort* l){
  __builtin_amdgcn_global_load_lds((gas1_t)(const void*)g, (las3_t)(void*)l, 16, 0, 0);
}

// ------ Kernel A: gates + q/k bf16 conversion + V^T bf16 (all fused) -------
// Block = 8 t-rows, 256 thr = 4 waves. Wave w owns gate rows {ig,fg}x{2w,2w+1}
// (weights read ONCE per block: 49MB L2 total). Wave0 writes q-bf16, wave1
// k-bf16, wave2 writes transposed V^T bf16 (replaces the vtrans kernel).
__global__ __launch_bounds__(256) void gates_qk(
    const float* __restrict__ q, const float* __restrict__ k, const float* __restrict__ v,
    const float* __restrict__ igw, const float* __restrict__ igb,
    const float* __restrict__ fgw, const float* __restrict__ fgb,
    float* __restrict__ ig_out, float* __restrict__ lsf_out,
    ushort* __restrict__ qbo, ushort* __restrict__ kbo, ushort* __restrict__ vto){
  const int t0 = blockIdx.x*8;
  const int tid = threadIdx.x;
  const int lane = tid & 63, w = tid >> 6;
  const float sc = 0.08838834764831845f;  // 1/sqrt(128)

  float acc[32];                       // a = (p*2+hh)*8 + r ; o = 2w+hh
  #pragma unroll
  for (int a=0;a<32;++a) acc[a]=0.f;

  const float4* wI0 = (const float4*)igw + (size_t)(2*w)*768;
  const float4* wI1 = (const float4*)igw + (size_t)(2*w+1)*768;
  const float4* wF0 = (const float4*)fgw + (size_t)(2*w)*768;
  const float4* wF1 = (const float4*)fgw + (size_t)(2*w+1)*768;

  #pragma unroll
  for (int step=0; step<3; ++step){
    const float* src = (step==0)? q : ((step==1)? k : v);
    #pragma unroll
    for (int i=0;i<4;++i){
      const int col = i*64 + lane;               // float4 column 0..255
      float4 in4[8];
      #pragma unroll
      for (int r=0;r<8;++r)
        in4[r] = ((const float4*)src)[(size_t)(t0+r)*256 + col];

      if (step==0 && w==0){
        #pragma unroll
        for (int r=0;r<8;++r){
          ushort4 o; o.x=f2bf(in4[r].x*sc); o.y=f2bf(in4[r].y*sc);
          o.z=f2bf(in4[r].z*sc); o.w=f2bf(in4[r].w*sc);
          ((ushort4*)qbo)[(size_t)(t0+r)*256 + col] = o;
        }
      } else if (step==1 && w==1){
        #pragma unroll
        for (int r=0;r<8;++r){
          ushort4 o; o.x=f2bf(in4[r].x); o.y=f2bf(in4[r].y);
          o.z=f2bf(in4[r].z); o.w=f2bf(in4[r].w);
          ((ushort4*)kbo)[(size_t)(t0+r)*256 + col] = o;
        }
      } else if (step==2 && w==2){
        // transposed V^T write: for each of 4 fp columns, 8 t-rows -> 16B
        #pragma unroll
        for (int c=0;c<4;++c){
          ushort tmp[8];
          tmp[0]=f2bf(c==0?in4[0].x:c==1?in4[0].y:c==2?in4[0].z:in4[0].w);
          tmp[1]=f2bf(c==0?in4[1].x:c==1?in4[1].y:c==2?in4[1].z:in4[1].w);
          tmp[2]=f2bf(c==0?in4[2].x:c==1?in4[2].y:c==2?in4[2].z:in4[2].w);
          tmp[3]=f2bf(c==0?in4[3].x:c==1?in4[3].y:c==2?in4[3].z:in4[3].w);
          tmp[4]=f2bf(c==0?in4[4].x:c==1?in4[4].y:c==2?in4[4].z:in4[4].w);
          tmp[5]=f2bf(c==0?in4[5].x:c==1?in4[5].y:c==2?in4[5].z:in4[5].w);
          tmp[6]=f2bf(c==0?in4[6].x:c==1?in4[6].y:c==2?in4[6].z:in4[6].w);
          tmp[7]=f2bf(c==0?in4[7].x:c==1?in4[7].y:c==2?in4[7].z:in4[7].w);
          uint4 ov; ushort* pp=(ushort*)&ov;
          #pragma unroll
          for (int z=0;z<8;++z) pp[z]=tmp[z];
          *(uint4*)(vto + (size_t)(col*4+c)*S_LEN + t0) = ov;
        }
      }

      const int jj = step*256 + col;
      const float4 a0 = wI0[jj], a1 = wI1[jj], b0 = wF0[jj], b1 = wF1[jj];
      #pragma unroll
      for (int r=0;r<8;++r){
        float x=in4[r].x, y=in4[r].y, z=in4[r].z, u=in4[r].w;
        acc[r]    = fmaf(x,a0.x,fmaf(y,a0.y,fmaf(z,a0.z,fmaf(u,a0.w,acc[r]))));
        acc[8+r]  = fmaf(x,a1.x,fmaf(y,a1.y,fmaf(z,a1.z,fmaf(u,a1.w,acc[8+r]))));
        acc[16+r] = fmaf(x,b0.x,fmaf(y,b0.y,fmaf(z,b0.z,fmaf(u,b0.w,acc[16+r]))));
        acc[24+r] = fmaf(x,b1.x,fmaf(y,b1.y,fmaf(z,b1.z,fmaf(u,b1.w,acc[24+r]))));
      }
    }
  }

  // 5-stage butterfly over 32 values within 32-lane groups, then xor-32 add.
  int cnt = 16;
  #pragma unroll
  for (int s=0; s<5; ++s){
    const bool hib = (lane >> s) & 1;
    #pragma unroll
    for (int a=0; a<16; ++a){
      if (a < cnt){
        float sent = hib ? acc[a] : acc[a+cnt];
        float got = __shfl_xor(sent, 1<<s, 64);
        acc[a] = (hib ? acc[a+cnt] : acc[a]) + got;
      }
    }
    cnt >>= 1;
  }
  acc[0] += __shfl_xor(acc[0], 32, 64);
  if (lane < 32){
    const int a = (int)(__brev((unsigned)lane) >> 27);   // bitrev5
    const int p = a >> 4, hh = (a>>3)&1, r = a&7;
    const int o = 2*w + hh;
    const int t = t0 + r;
    if (p==0) ig_out[o*S_LEN + t] = acc[0] + igb[o];
    else      lsf_out[o*S_LEN + t] = logsigf(acc[0] + fgb[o]);
  }
}

// ---------------- Kernel B: per-head scans ---------------------------------
__global__ __launch_bounds__(256) void scan_kernel(
    const float* __restrict__ ig, const float* __restrict__ lsf,
    float* __restrict__ cs_out, float* __restrict__ M_out, float* __restrict__ m_out){
  const int h = blockIdx.x;
  const int tid = threadIdx.x;
  __shared__ float tt[256];
  const int base = tid*8;
  const float* src = lsf + h*S_LEN;
  float loc[8]; float tot = 0.f;
  #pragma unroll
  for (int i=0;i<8;++i){ tot += src[base+i]; loc[i]=tot; }
  tt[tid]=tot; __syncthreads();
  for (int off=1; off<256; off<<=1){
    float add = (tid>=off)? tt[tid-off] : 0.f;
    __syncthreads();
    tt[tid] += add;
    __syncthreads();
  }
  const float excl = tt[tid] - tot;
  float csv[8];
  #pragma unroll
  for (int i=0;i<8;++i){ csv[i] = excl + loc[i]; cs_out[h*S_LEN+base+i]=csv[i]; }
  const float* igp = ig + h*S_LEN;
  float mloc[8], mval[8]; float mtot = -INFINITY;
  #pragma unroll
  for (int i=0;i<8;++i){
    float m = igp[base+i] - csv[i];
    mval[i] = m;
    mtot = fmaxf(mtot, m);
    mloc[i] = mtot;
  }
  __syncthreads();
  tt[tid]=mtot; __syncthreads();
  for (int off=1; off<256; off<<=1){
    float add = (tid>=off)? tt[tid-off] : -INFINITY;
    __syncthreads();
    tt[tid] = fmaxf(tt[tid], add);
    __syncthreads();
  }
  const float exclm = (tid>0)? tt[tid-1] : -INFINITY;
  #pragma unroll
  for (int i=0;i<8;++i){
    M_out[h*S_LEN+base+i] = fmaxf(exclm, mloc[i]);
    m_out[h*S_LEN+base+i] = mval[i];
  }
}

// ---------------- Kernel C: r9 measured-best structure (unchanged) ---------
__global__ __launch_bounds__(256, 2) void mlstm_mfma6(
    const ushort* __restrict__ qb, const ushort* __restrict__ kb,
    const ushort* __restrict__ vt,
    const float* __restrict__ csb, const float* __restrict__ Mxb,
    const float* __restrict__ mbb,
    const float* __restrict__ nw, float* __restrict__ out){
  const int h = blockIdx.x;
  const int qt = 63 - blockIdx.y;            // LPT: biggest q-tile first
  const int tid = threadIdx.x, l = tid & 63;
  const int sq = tid >> 6;                   // wave = s-quarter 0..3
  const int l31 = l & 31, l15 = l & 15, hi = l >> 5;

  __shared__ __align__(16) float UNI[4*32*132];   // 67584 B union
  __shared__ float MB[128];
  __shared__ float rsL[4][32];
  ushort* Kb = (ushort*)UNI;                 // 32 KB: [128 s][16 chunks]
  ushort* Vb = Kb + 16384;                   // 32 KB: [128 d][16 chunks]
  float*  Part = UNI;                        // [4 w][32 q][132]

  const int hS = h*S_LEN;
  const ushort* kbh = kb + h*DH;
  const ushort* vth = vt + (size_t)h*DH*S_LEN;
  const float*  mh  = mbb + hS;
  const int t0 = qt*32;
  const int NT = (t0 + 31)/128 + 1;
  const int tgq = t0 + l31;
  const float Mq = Mxb[hS + tgq];

  bf16x8 qf0,qf1,qf2,qf3,qf4,qf5,qf6,qf7;
  { const ushort* qs = qb + (size_t)tgq*E_DIM + h*DH + hi*8;
    qf0 = *(const bf16x8*)(qs+0);   qf1 = *(const bf16x8*)(qs+16);
    qf2 = *(const bf16x8*)(qs+32);  qf3 = *(const bf16x8*)(qs+48);
    qf4 = *(const bf16x8*)(qs+64);  qf5 = *(const bf16x8*)(qs+80);
    qf6 = *(const bf16x8*)(qs+96);  qf7 = *(const bf16x8*)(qs+112); }

  f32x16 a0 = Z16, a1 = Z16, a2 = Z16, a3 = Z16;
  float rsq = 0.f;

#define STAGE6(ktv) {                                                        \
    _Pragma("unroll")                                                        \
    for (int i_=0;i_<8;++i_){                                                \
      const int L_ = tid + i_*256; const int row_ = L_>>4, pc_ = L_&15;      \
      stage16(kbh + (size_t)((ktv)*128+row_)*E_DIM + ((pc_^(row_&15))<<3),   \
              Kb + (size_t)L_*8); }                                          \
    _Pragma("unroll")                                                        \
    for (int i_=0;i_<8;++i_){                                                \
      const int L_ = tid + i_*256; const int d_ = L_>>4, pc_ = L_&15;        \
      stage16(vth + (size_t)d_*S_LEN + (ktv)*128 + ((pc_^(d_&15))<<3),       \
              Vb + (size_t)L_*8); }                                          \
    if (tid < 32)                                                            \
      stage16((const ushort*)(mh + (ktv)*128) + tid*8,                       \
              (ushort*)MB + tid*8); }

#define LV6(dt, cs) (*(const bf16x8*)(Vb + (size_t)((dt)*32+l31)*128 + (((cs)^l15)<<3)))

  for (int kt=0; kt<NT; ++kt){
    if (kt) __syncthreads();                 // prev tile's LDS readers done
    STAGE6(kt);
    __syncthreads();                         // stage landed (vmcnt drained)

    const ushort* kbase = Kb + (size_t)(sq*32 + l31)*128;
    f32x16 cc = Z16;
    { bf16x8 ka;
      ka = *(const bf16x8*)(kbase + (((0*2+hi)^l15)<<3)); cc = MFMA3216(ka, qf0, cc);
      ka = *(const bf16x8*)(kbase + (((1*2+hi)^l15)<<3)); cc = MFMA3216(ka, qf1, cc);
      ka = *(const bf16x8*)(kbase + (((2*2+hi)^l15)<<3)); cc = MFMA3216(ka, qf2, cc);
      ka = *(const bf16x8*)(kbase + (((3*2+hi)^l15)<<3)); cc = MFMA3216(ka, qf3, cc);
      ka = *(const bf16x8*)(kbase + (((4*2+hi)^l15)<<3)); cc = MFMA3216(ka, qf4, cc);
      ka = *(const bf16x8*)(kbase + (((5*2+hi)^l15)<<3)); cc = MFMA3216(ka, qf5, cc);
      ka = *(const bf16x8*)(kbase + (((6*2+hi)^l15)<<3)); cc = MFMA3216(ka, qf6, cc);
      ka = *(const bf16x8*)(kbase + (((7*2+hi)^l15)<<3)); cc = MFMA3216(ka, qf7, cc); }

    bf16x8 fE, fO;
    {
      const int sb_ = kt*128 + sq*32 + 4*hi;
      const f32x4 mA_ = *(const f32x4*)&MB[sq*32 +  0 + 4*hi];
      const f32x4 mB_ = *(const f32x4*)&MB[sq*32 +  8 + 4*hi];
      const f32x4 mC_ = *(const f32x4*)&MB[sq*32 + 16 + 4*hi];
      const f32x4 mD_ = *(const f32x4*)&MB[sq*32 + 24 + 4*hi];
      float p0  = (sb_+0  <= tgq) ? cc[0] *__expf(mA_[0]-Mq) : 0.f;
      float p1  = (sb_+1  <= tgq) ? cc[1] *__expf(mA_[1]-Mq) : 0.f;
      float p2  = (sb_+2  <= tgq) ? cc[2] *__expf(mA_[2]-Mq) : 0.f;
      float p3  = (sb_+3  <= tgq) ? cc[3] *__expf(mA_[3]-Mq) : 0.f;
      float p4  = (sb_+8  <= tgq) ? cc[4] *__expf(mB_[0]-Mq) : 0.f;
      float p5  = (sb_+9  <= tgq) ? cc[5] *__expf(mB_[1]-Mq) : 0.f;
      float p6  = (sb_+10 <= tgq) ? cc[6] *__expf(mB_[2]-Mq) : 0.f;
      float p7  = (sb_+11 <= tgq) ? cc[7] *__expf(mB_[3]-Mq) : 0.f;
      float p8  = (sb_+16 <= tgq) ? cc[8] *__expf(mC_[0]-Mq) : 0.f;
      float p9  = (sb_+17 <= tgq) ? cc[9] *__expf(mC_[1]-Mq) : 0.f;
      float p10 = (sb_+18 <= tgq) ? cc[10]*__expf(mC_[2]-Mq) : 0.f;
      float p11 = (sb_+19 <= tgq) ? cc[11]*__expf(mC_[3]-Mq) : 0.f;
      float p12 = (sb_+24 <= tgq) ? cc[12]*__expf(mD_[0]-Mq) : 0.f;
      float p13 = (sb_+25 <= tgq) ? cc[13]*__expf(mD_[1]-Mq) : 0.f;
      float p14 = (sb_+26 <= tgq) ? cc[14]*__expf(mD_[2]-Mq) : 0.f;
      float p15 = (sb_+27 <= tgq) ? cc[15]*__expf(mD_[3]-Mq) : 0.f;
      rsq += ((p0+p1)+(p2+p3))+((p4+p5)+(p6+p7))
           + ((p8+p9)+(p10+p11))+((p12+p13)+(p14+p15));
      unsigned A0_=cvtpk(p0,p1),  A1_=cvtpk(p2,p3);
      unsigned B0_=cvtpk(p4,p5),  B1_=cvtpk(p6,p7);
      unsigned C0_=cvtpk(p8,p9),  C1_=cvtpk(p10,p11);
      unsigned D0_=cvtpk(p12,p13),D1_=cvtpk(p14,p15);
      unsigned A0x_=(unsigned)__shfl_xor((int)A0_,32,64);
      unsigned B0x_=(unsigned)__shfl_xor((int)B0_,32,64);
      unsigned A1x_=(unsigned)__shfl_xor((int)A1_,32,64);
      unsigned B1x_=(unsigned)__shfl_xor((int)B1_,32,64);
      unsigned C0x_=(unsigned)__shfl_xor((int)C0_,32,64);
      unsigned D0x_=(unsigned)__shfl_xor((int)D0_,32,64);
      unsigned C1x_=(unsigned)__shfl_xor((int)C1_,32,64);
      unsigned D1x_=(unsigned)__shfl_xor((int)D1_,32,64);
      { unsigned* u_ = (unsigned*)&fE;
        u_[0] = hi ? B0x_ : A0_;  u_[1] = hi ? B1x_ : A1_;
        u_[2] = hi ? B0_  : A0x_; u_[3] = hi ? B1_  : A1x_; }
      { unsigned* u_ = (unsigned*)&fO;
        u_[0] = hi ? D0x_ : C0_;  u_[1] = hi ? D1x_ : C1_;
        u_[2] = hi ? D0_  : C0x_; u_[3] = hi ? D1_  : C1x_; }
    }

    a0 = MFMA3216(fE, LV6(0, sq*4 + 0 + hi), a0);
    a1 = MFMA3216(fE, LV6(1, sq*4 + 0 + hi), a1);
    a2 = MFMA3216(fE, LV6(2, sq*4 + 0 + hi), a2);
    a3 = MFMA3216(fE, LV6(3, sq*4 + 0 + hi), a3);
    a0 = MFMA3216(fO, LV6(0, sq*4 + 2 + hi), a0);
    a1 = MFMA3216(fO, LV6(1, sq*4 + 2 + hi), a1);
    a2 = MFMA3216(fO, LV6(2, sq*4 + 2 + hi), a2);
    a3 = MFMA3216(fO, LV6(3, sq*4 + 2 + hi), a3);
  }

  // -------- epilogue: cross-wave reduce (LDS union) + normalizer + LN ------
  __syncthreads();
  #pragma unroll
  for (int r=0;r<16;++r){
    const int qrow = CROW(r) + 4*hi;
    float* pr = Part + (size_t)(sq*32 + qrow)*132 + l31;
    pr[0]  = a0[r];
    pr[32] = a1[r];
    pr[64] = a2[r];
    pr[96] = a3[r];
  }
  rsq += __shfl_xor(rsq, 32, 64);
  if (l < 32) rsL[sq][l31] = rsq;
  __syncthreads();

  {
    const int q = tid >> 3, dg = tid & 7;
    f32x4 os0={0.f,0.f,0.f,0.f}, os1=os0, os2=os0, os3=os0;
    #pragma unroll
    for (int w2=0; w2<4; ++w2){
      const float* pb = Part + (size_t)(w2*32 + q)*132 + dg*16;
      os0 += *(const f32x4*)(pb+0);
      os1 += *(const f32x4*)(pb+4);
      os2 += *(const f32x4*)(pb+8);
      os3 += *(const f32x4*)(pb+12);
    }
    const float rstot = rsL[0][q]+rsL[1][q]+rsL[2][q]+rsL[3][q];
    const int tq = t0 + q;
    const float en = __expf(-(csb[hS+tq] + Mxb[hS+tq]));
    const float iv = 1.f/(fmaxf(fabsf(rstot), en) + 1e-6f);
    f32x4 h0, h1, h2, h3;
    h0[0]=os0[0]*iv; h0[1]=os0[1]*iv; h0[2]=os0[2]*iv; h0[3]=os0[3]*iv;
    h1[0]=os1[0]*iv; h1[1]=os1[1]*iv; h1[2]=os1[2]*iv; h1[3]=os1[3]*iv;
    h2[0]=os2[0]*iv; h2[1]=os2[1]*iv; h2[2]=os2[2]*iv; h2[3]=os2[3]*iv;
    h3[0]=os3[0]*iv; h3[1]=os3[1]*iv; h3[2]=os3[2]*iv; h3[3]=os3[3]*iv;
    float s1 = (h0[0]+h0[1]+h0[2]+h0[3]) + (h1[0]+h1[1]+h1[2]+h1[3])
             + (h2[0]+h2[1]+h2[2]+h2[3]) + (h3[0]+h3[1]+h3[2]+h3[3]);
    float s2 = (h0[0]*h0[0]+h0[1]*h0[1]+h0[2]*h0[2]+h0[3]*h0[3])
             + (h1[0]*h1[0]+h1[1]*h1[1]+h1[2]*h1[2]+h1[3]*h1[3])
             + (h2[0]*h2[0]+h2[1]*h2[1]+h2[2]*h2[2]+h2[3]*h2[3])
             + (h3[0]*h3[0]+h3[1]*h3[1]+h3[2]*h3[2]+h3[3]*h3[3]);
    s1 += __shfl_xor(s1, 1, 64);  s2 += __shfl_xor(s2, 1, 64);
    s1 += __shfl_xor(s1, 2, 64);  s2 += __shfl_xor(s2, 2, 64);
    s1 += __shfl_xor(s1, 4, 64);  s2 += __shfl_xor(s2, 4, 64);
    const float mean = s1*(1.f/128.f);
    const float var  = s2*(1.f/128.f) - mean*mean;
    const float rstd = rsqrtf(var + 1e-5f);
    const float* nb = nw + h*DH + dg*16;
    const f32x4 n0 = *(const f32x4*)(nb+0);
    const f32x4 n1 = *(const f32x4*)(nb+4);
    const f32x4 n2 = *(const f32x4*)(nb+8);
    const f32x4 n3 = *(const f32x4*)(nb+12);
    float* ob = out + (size_t)tq*E_DIM + h*DH + dg*16;
    f32x4 o0v, o1v, o2v, o3v;
    o0v[0]=(h0[0]-mean)*rstd*n0[0]; o0v[1]=(h0[1]-mean)*rstd*n0[1];
    o0v[2]=(h0[2]-mean)*rstd*n0[2]; o0v[3]=(h0[3]-mean)*rstd*n0[3];
    o1v[0]=(h1[0]-mean)*rstd*n1[0]; o1v[1]=(h1[1]-mean)*rstd*n1[1];
    o1v[2]=(h1[2]-mean)*rstd*n1[2]; o1v[3]=(h1[3]-mean)*rstd*n1[3];
    o2v[0]=(h2[0]-mean)*rstd*n2[0]; o2v[1]=(h2[1]-mean)*rstd*n2[1];
    o2v[2]=(h2[2]-mean)*rstd*n2[2]; o2v[3]=(h2[3]-mean)*rstd*n2[3];
    o3v[0]=(h3[0]-mean)*rstd*n3[0]; o3v[1]=(h3[1]-mean)*rstd*n3[1];
    o3v[2]=(h3[2]-mean)*rstd*n3[2]; o3v[3]=(h3[3]-mean)*rstd*n3[3];
    *(f32x4*)(ob+0)  = o0v;
    *(f32x4*)(ob+4)  = o1v;
    *(f32x4*)(ob+8)  = o2v;
    *(f32x4*)(ob+12) = o3v;
  }
}

extern "C" void kernel_launch(void* const* d_in, const int* in_sizes, int n_in,
                              void* d_out, int out_size, void* d_ws, size_t ws_size,
                              hipStream_t stream) {
  const float* q   = (const float*)d_in[0];
  const float* k   = (const float*)d_in[1];
  const float* v   = (const float*)d_in[2];
  const float* igw = (const float*)d_in[3];
  const float* igb = (const float*)d_in[4];
  const float* fgw = (const float*)d_in[5];
  const float* fgb = (const float*)d_in[6];
  const float* nw  = (const float*)d_in[7];
  float* outp = (float*)d_out;

  float* ws  = (float*)d_ws;
  float* ig  = ws;                 // NH*S
  float* lsf = ws + 1*NHEAD*S_LEN;
  float* csb = ws + 2*NHEAD*S_LEN;
  float* Mb  = ws + 3*NHEAD*S_LEN;
  float* mbf = ws + 4*NHEAD*S_LEN;
  ushort* qbb = (ushort*)(ws + 5*NHEAD*S_LEN);          // S*E bf16 (scaled)
  ushort* kbb = qbb + (size_t)S_LEN*E_DIM;              // S*E bf16
  ushort* vtb = kbb + (size_t)S_LEN*E_DIM;              // E*S bf16 (per-head V^T)

  gates_qk<<<S_LEN/8, 256, 0, stream>>>(q, k, v, igw, igb, fgw, fgb,
                                        ig, lsf, qbb, kbb, vtb);
  scan_kernel<<<NHEAD, 256, 0, stream>>>(ig, lsf, csb, Mb, mbf);
  mlstm_mfma6<<<dim3(NHEAD, 64), 256, 0, stream>>>(qbb, kbb, vtb, csb, Mb, mbf, nw, outp);
}

// Round 14
// 67.049 us; speedup vs baseline: 1.1279x; 1.1279x over previous
//
#include <hip/hip_runtime.h>
#include <hip/hip_bf16.h>
#include <math.h>

#define S_LEN 2048
#define E_DIM 1024
#define NHEAD 8
#define DH 128
#define E3 3072

typedef short bf16x8 __attribute__((ext_vector_type(8)));
typedef short bf16x4 __attribute__((ext_vector_type(4)));
typedef float f32x4 __attribute__((ext_vector_type(4)));
typedef float f32x16 __attribute__((ext_vector_type(16)));

#define MFMA3216(a,b,c) __builtin_amdgcn_mfma_f32_32x32x16_bf16(a,b,c,0,0,0)
#define Z16 {0.f,0.f,0.f,0.f,0.f,0.f,0.f,0.f,0.f,0.f,0.f,0.f,0.f,0.f,0.f,0.f}
#define CROW(r) (((r)&3) + 8*((r)>>2))

__device__ __forceinline__ unsigned short f2bf(float f){
  union{float f; unsigned u;} x; x.f = f;
  unsigned r = x.u + 0x7FFF + ((x.u>>16)&1);
  return (unsigned short)(r>>16);
}

__device__ __forceinline__ unsigned cvtpk(float lo, float hi){
  unsigned r;
  asm("v_cvt_pk_bf16_f32 %0, %1, %2" : "=v"(r) : "v"(lo), "v"(hi));
  return r;
}

__device__ __forceinline__ float logsigf(float x){
  return fminf(x, 0.f) - log1pf(expf(-fabsf(x)));
}

typedef const __attribute__((address_space(1))) unsigned int* gas1_t;
typedef __attribute__((address_space(3))) unsigned int* las3_t;
__device__ __forceinline__ void stage16(const ushort* g, ushort* l){
  __builtin_amdgcn_global_load_lds((gas1_t)(const void*)g, (las3_t)(void*)l, 16, 0, 0);
}

// ------ Kernel A: gates + q/k bf16 + V^T bf16, low-register version --------
// Block = 4 t-rows, 256 thr = 4 waves. Wave w owns gate rows {ig,fg}x{2w,2w+1}
// -> acc[16] per thread (no spill; r13's acc[32]+in4[8] spilled 31MB scratch).
// Each wave streams ALL input columns (L2 re-read, cheap); weights read once
// per block. Wave0 writes q-bf16, wave1 k-bf16, wave2 transposed V^T.
__global__ __launch_bounds__(256) void gates_qk(
    const float* __restrict__ q, const float* __restrict__ k, const float* __restrict__ v,
    const float* __restrict__ igw, const float* __restrict__ igb,
    const float* __restrict__ fgw, const float* __restrict__ fgb,
    float* __restrict__ ig_out, float* __restrict__ lsf_out,
    ushort* __restrict__ qbo, ushort* __restrict__ kbo, ushort* __restrict__ vto){
  const int t0 = blockIdx.x*4;
  const int tid = threadIdx.x;
  const int lane = tid & 63, w = tid >> 6;
  const float sc = 0.08838834764831845f;  // 1/sqrt(128)

  float acc[16];
  #pragma unroll
  for (int a=0;a<16;++a) acc[a]=0.f;

  const float4* wI0 = (const float4*)igw + (size_t)(2*w)*768;
  const float4* wI1 = wI0 + 768;
  const float4* wF0 = (const float4*)fgw + (size_t)(2*w)*768;
  const float4* wF1 = wF0 + 768;

  #pragma unroll
  for (int step=0; step<3; ++step){
    const float* src = (step==0)? q : ((step==1)? k : v);
    #pragma unroll
    for (int ch=0; ch<4; ++ch){
      const int col = ch*64 + lane;              // float4 column 0..255
      float4 in4[4];
      #pragma unroll
      for (int r=0;r<4;++r)
        in4[r] = ((const float4*)src)[(size_t)(t0+r)*256 + col];

      if (step==0 && w==0){
        #pragma unroll
        for (int r=0;r<4;++r){
          ushort4 o; o.x=f2bf(in4[r].x*sc); o.y=f2bf(in4[r].y*sc);
          o.z=f2bf(in4[r].z*sc); o.w=f2bf(in4[r].w*sc);
          ((ushort4*)qbo)[(size_t)(t0+r)*256 + col] = o;
        }
      } else if (step==1 && w==1){
        #pragma unroll
        for (int r=0;r<4;++r){
          ushort4 o; o.x=f2bf(in4[r].x); o.y=f2bf(in4[r].y);
          o.z=f2bf(in4[r].z); o.w=f2bf(in4[r].w);
          ((ushort4*)kbo)[(size_t)(t0+r)*256 + col] = o;
        }
      } else if (step==2 && w==2){
        // transposed V^T: d = col*4+c (global over E), 4 t-rows -> 8B store
        #pragma unroll
        for (int c=0;c<4;++c){
          ushort4 ov;
          ov.x = f2bf(c==0?in4[0].x:c==1?in4[0].y:c==2?in4[0].z:in4[0].w);
          ov.y = f2bf(c==0?in4[1].x:c==1?in4[1].y:c==2?in4[1].z:in4[1].w);
          ov.z = f2bf(c==0?in4[2].x:c==1?in4[2].y:c==2?in4[2].z:in4[2].w);
          ov.w = f2bf(c==0?in4[3].x:c==1?in4[3].y:c==2?in4[3].z:in4[3].w);
          *(ushort4*)(vto + (size_t)(col*4+c)*S_LEN + t0) = ov;
        }
      }

      const int jj = step*256 + col;
      const float4 a0 = wI0[jj], a1 = wI1[jj], b0 = wF0[jj], b1 = wF1[jj];
      #pragma unroll
      for (int r=0;r<4;++r){
        const float x=in4[r].x, y=in4[r].y, z=in4[r].z, u=in4[r].w;
        acc[r]    = fmaf(x,a0.x,fmaf(y,a0.y,fmaf(z,a0.z,fmaf(u,a0.w,acc[r]))));
        acc[4+r]  = fmaf(x,a1.x,fmaf(y,a1.y,fmaf(z,a1.z,fmaf(u,a1.w,acc[4+r]))));
        acc[8+r]  = fmaf(x,b0.x,fmaf(y,b0.y,fmaf(z,b0.z,fmaf(u,b0.w,acc[8+r]))));
        acc[12+r] = fmaf(x,b1.x,fmaf(y,b1.y,fmaf(z,b1.z,fmaf(u,b1.w,acc[12+r]))));
      }
    }
  }

  // simple per-value 64-lane tree reduction; lane 0 writes its wave's rows
  #pragma unroll
  for (int a=0;a<16;++a){
    acc[a] += __shfl_down(acc[a], 1, 64);
    acc[a] += __shfl_down(acc[a], 2, 64);
    acc[a] += __shfl_down(acc[a], 4, 64);
    acc[a] += __shfl_down(acc[a], 8, 64);
    acc[a] += __shfl_down(acc[a], 16, 64);
    acc[a] += __shfl_down(acc[a], 32, 64);
  }
  if (lane == 0){
    #pragma unroll
    for (int ol=0; ol<2; ++ol){
      const int o = 2*w + ol;
      #pragma unroll
      for (int r=0;r<4;++r){
        ig_out[o*S_LEN + t0 + r]  = acc[ol*4+r] + igb[o];
        lsf_out[o*S_LEN + t0 + r] = logsigf(acc[8+ol*4+r] + fgb[o]);
      }
    }
  }
}

// ---------------- Kernel B: per-head scans ---------------------------------
__global__ __launch_bounds__(256) void scan_kernel(
    const float* __restrict__ ig, const float* __restrict__ lsf,
    float* __restrict__ cs_out, float* __restrict__ M_out, float* __restrict__ m_out){
  const int h = blockIdx.x;
  const int tid = threadIdx.x;
  __shared__ float tt[256];
  const int base = tid*8;
  const float* src = lsf + h*S_LEN;
  float loc[8]; float tot = 0.f;
  #pragma unroll
  for (int i=0;i<8;++i){ tot += src[base+i]; loc[i]=tot; }
  tt[tid]=tot; __syncthreads();
  for (int off=1; off<256; off<<=1){
    float add = (tid>=off)? tt[tid-off] : 0.f;
    __syncthreads();
    tt[tid] += add;
    __syncthreads();
  }
  const float excl = tt[tid] - tot;
  float csv[8];
  #pragma unroll
  for (int i=0;i<8;++i){ csv[i] = excl + loc[i]; cs_out[h*S_LEN+base+i]=csv[i]; }
  const float* igp = ig + h*S_LEN;
  float mloc[8], mval[8]; float mtot = -INFINITY;
  #pragma unroll
  for (int i=0;i<8;++i){
    float m = igp[base+i] - csv[i];
    mval[i] = m;
    mtot = fmaxf(mtot, m);
    mloc[i] = mtot;
  }
  __syncthreads();
  tt[tid]=mtot; __syncthreads();
  for (int off=1; off<256; off<<=1){
    float add = (tid>=off)? tt[tid-off] : -INFINITY;
    __syncthreads();
    tt[tid] = fmaxf(tt[tid], add);
    __syncthreads();
  }
  const float exclm = (tid>0)? tt[tid-1] : -INFINITY;
  #pragma unroll
  for (int i=0;i<8;++i){
    M_out[h*S_LEN+base+i] = fmaxf(exclm, mloc[i]);
    m_out[h*S_LEN+base+i] = mval[i];
  }
}

// ---------------- Kernel C: r9 measured-best structure (unchanged) ---------
__global__ __launch_bounds__(256, 2) void mlstm_mfma6(
    const ushort* __restrict__ qb, const ushort* __restrict__ kb,
    const ushort* __restrict__ vt,
    const float* __restrict__ csb, const float* __restrict__ Mxb,
    const float* __restrict__ mbb,
    const float* __restrict__ nw, float* __restrict__ out){
  const int h = blockIdx.x;
  const int qt = 63 - blockIdx.y;            // LPT: biggest q-tile first
  const int tid = threadIdx.x, l = tid & 63;
  const int sq = tid >> 6;                   // wave = s-quarter 0..3
  const int l31 = l & 31, l15 = l & 15, hi = l >> 5;

  __shared__ __align__(16) float UNI[4*32*132];   // 67584 B union
  __shared__ float MB[128];
  __shared__ float rsL[4][32];
  ushort* Kb = (ushort*)UNI;                 // 32 KB: [128 s][16 chunks]
  ushort* Vb = Kb + 16384;                   // 32 KB: [128 d][16 chunks]
  float*  Part = UNI;                        // [4 w][32 q][132]

  const int hS = h*S_LEN;
  const ushort* kbh = kb + h*DH;
  const ushort* vth = vt + (size_t)h*DH*S_LEN;
  const float*  mh  = mbb + hS;
  const int t0 = qt*32;
  const int NT = (t0 + 31)/128 + 1;
  const int tgq = t0 + l31;
  const float Mq = Mxb[hS + tgq];

  bf16x8 qf0,qf1,qf2,qf3,qf4,qf5,qf6,qf7;
  { const ushort* qs = qb + (size_t)tgq*E_DIM + h*DH + hi*8;
    qf0 = *(const bf16x8*)(qs+0);   qf1 = *(const bf16x8*)(qs+16);
    qf2 = *(const bf16x8*)(qs+32);  qf3 = *(const bf16x8*)(qs+48);
    qf4 = *(const bf16x8*)(qs+64);  qf5 = *(const bf16x8*)(qs+80);
    qf6 = *(const bf16x8*)(qs+96);  qf7 = *(const bf16x8*)(qs+112); }

  f32x16 a0 = Z16, a1 = Z16, a2 = Z16, a3 = Z16;
  float rsq = 0.f;

#define STAGE6(ktv) {                                                        \
    _Pragma("unroll")                                                        \
    for (int i_=0;i_<8;++i_){                                                \
      const int L_ = tid + i_*256; const int row_ = L_>>4, pc_ = L_&15;      \
      stage16(kbh + (size_t)((ktv)*128+row_)*E_DIM + ((pc_^(row_&15))<<3),   \
              Kb + (size_t)L_*8); }                                          \
    _Pragma("unroll")                                                        \
    for (int i_=0;i_<8;++i_){                                                \
      const int L_ = tid + i_*256; const int d_ = L_>>4, pc_ = L_&15;        \
      stage16(vth + (size_t)d_*S_LEN + (ktv)*128 + ((pc_^(d_&15))<<3),       \
              Vb + (size_t)L_*8); }                                          \
    if (tid < 32)                                                            \
      stage16((const ushort*)(mh + (ktv)*128) + tid*8,                       \
              (ushort*)MB + tid*8); }

#define LV6(dt, cs) (*(const bf16x8*)(Vb + (size_t)((dt)*32+l31)*128 + (((cs)^l15)<<3)))

  for (int kt=0; kt<NT; ++kt){
    if (kt) __syncthreads();                 // prev tile's LDS readers done
    STAGE6(kt);
    __syncthreads();                         // stage landed (vmcnt drained)

    const ushort* kbase = Kb + (size_t)(sq*32 + l31)*128;
    f32x16 cc = Z16;
    { bf16x8 ka;
      ka = *(const bf16x8*)(kbase + (((0*2+hi)^l15)<<3)); cc = MFMA3216(ka, qf0, cc);
      ka = *(const bf16x8*)(kbase + (((1*2+hi)^l15)<<3)); cc = MFMA3216(ka, qf1, cc);
      ka = *(const bf16x8*)(kbase + (((2*2+hi)^l15)<<3)); cc = MFMA3216(ka, qf2, cc);
      ka = *(const bf16x8*)(kbase + (((3*2+hi)^l15)<<3)); cc = MFMA3216(ka, qf3, cc);
      ka = *(const bf16x8*)(kbase + (((4*2+hi)^l15)<<3)); cc = MFMA3216(ka, qf4, cc);
      ka = *(const bf16x8*)(kbase + (((5*2+hi)^l15)<<3)); cc = MFMA3216(ka, qf5, cc);
      ka = *(const bf16x8*)(kbase + (((6*2+hi)^l15)<<3)); cc = MFMA3216(ka, qf6, cc);
      ka = *(const bf16x8*)(kbase + (((7*2+hi)^l15)<<3)); cc = MFMA3216(ka, qf7, cc); }

    bf16x8 fE, fO;
    {
      const int sb_ = kt*128 + sq*32 + 4*hi;
      const f32x4 mA_ = *(const f32x4*)&MB[sq*32 +  0 + 4*hi];
      const f32x4 mB_ = *(const f32x4*)&MB[sq*32 +  8 + 4*hi];
      const f32x4 mC_ = *(const f32x4*)&MB[sq*32 + 16 + 4*hi];
      const f32x4 mD_ = *(const f32x4*)&MB[sq*32 + 24 + 4*hi];
      float p0  = (sb_+0  <= tgq) ? cc[0] *__expf(mA_[0]-Mq) : 0.f;
      float p1  = (sb_+1  <= tgq) ? cc[1] *__expf(mA_[1]-Mq) : 0.f;
      float p2  = (sb_+2  <= tgq) ? cc[2] *__expf(mA_[2]-Mq) : 0.f;
      float p3  = (sb_+3  <= tgq) ? cc[3] *__expf(mA_[3]-Mq) : 0.f;
      float p4  = (sb_+8  <= tgq) ? cc[4] *__expf(mB_[0]-Mq) : 0.f;
      float p5  = (sb_+9  <= tgq) ? cc[5] *__expf(mB_[1]-Mq) : 0.f;
      float p6  = (sb_+10 <= tgq) ? cc[6] *__expf(mB_[2]-Mq) : 0.f;
      float p7  = (sb_+11 <= tgq) ? cc[7] *__expf(mB_[3]-Mq) : 0.f;
      float p8  = (sb_+16 <= tgq) ? cc[8] *__expf(mC_[0]-Mq) : 0.f;
      float p9  = (sb_+17 <= tgq) ? cc[9] *__expf(mC_[1]-Mq) : 0.f;
      float p10 = (sb_+18 <= tgq) ? cc[10]*__expf(mC_[2]-Mq) : 0.f;
      float p11 = (sb_+19 <= tgq) ? cc[11]*__expf(mC_[3]-Mq) : 0.f;
      float p12 = (sb_+24 <= tgq) ? cc[12]*__expf(mD_[0]-Mq) : 0.f;
      float p13 = (sb_+25 <= tgq) ? cc[13]*__expf(mD_[1]-Mq) : 0.f;
      float p14 = (sb_+26 <= tgq) ? cc[14]*__expf(mD_[2]-Mq) : 0.f;
      float p15 = (sb_+27 <= tgq) ? cc[15]*__expf(mD_[3]-Mq) : 0.f;
      rsq += ((p0+p1)+(p2+p3))+((p4+p5)+(p6+p7))
           + ((p8+p9)+(p10+p11))+((p12+p13)+(p14+p15));
      unsigned A0_=cvtpk(p0,p1),  A1_=cvtpk(p2,p3);
      unsigned B0_=cvtpk(p4,p5),  B1_=cvtpk(p6,p7);
      unsigned C0_=cvtpk(p8,p9),  C1_=cvtpk(p10,p11);
      unsigned D0_=cvtpk(p12,p13),D1_=cvtpk(p14,p15);
      unsigned A0x_=(unsigned)__shfl_xor((int)A0_,32,64);
      unsigned B0x_=(unsigned)__shfl_xor((int)B0_,32,64);
      unsigned A1x_=(unsigned)__shfl_xor((int)A1_,32,64);
      unsigned B1x_=(unsigned)__shfl_xor((int)B1_,32,64);
      unsigned C0x_=(unsigned)__shfl_xor((int)C0_,32,64);
      unsigned D0x_=(unsigned)__shfl_xor((int)D0_,32,64);
      unsigned C1x_=(unsigned)__shfl_xor((int)C1_,32,64);
      unsigned D1x_=(unsigned)__shfl_xor((int)D1_,32,64);
      { unsigned* u_ = (unsigned*)&fE;
        u_[0] = hi ? B0x_ : A0_;  u_[1] = hi ? B1x_ : A1_;
        u_[2] = hi ? B0_  : A0x_; u_[3] = hi ? B1_  : A1x_; }
      { unsigned* u_ = (unsigned*)&fO;
        u_[0] = hi ? D0x_ : C0_;  u_[1] = hi ? D1x_ : C1_;
        u_[2] = hi ? D0_  : C0x_; u_[3] = hi ? D1_  : C1x_; }
    }

    a0 = MFMA3216(fE, LV6(0, sq*4 + 0 + hi), a0);
    a1 = MFMA3216(fE, LV6(1, sq*4 + 0 + hi), a1);
    a2 = MFMA3216(fE, LV6(2, sq*4 + 0 + hi), a2);
    a3 = MFMA3216(fE, LV6(3, sq*4 + 0 + hi), a3);
    a0 = MFMA3216(fO, LV6(0, sq*4 + 2 + hi), a0);
    a1 = MFMA3216(fO, LV6(1, sq*4 + 2 + hi), a1);
    a2 = MFMA3216(fO, LV6(2, sq*4 + 2 + hi), a2);
    a3 = MFMA3216(fO, LV6(3, sq*4 + 2 + hi), a3);
  }

  // -------- epilogue: cross-wave reduce (LDS union) + normalizer + LN ------
  __syncthreads();
  #pragma unroll
  for (int r=0;r<16;++r){
    const int qrow = CROW(r) + 4*hi;
    float* pr = Part + (size_t)(sq*32 + qrow)*132 + l31;
    pr[0]  = a0[r];
    pr[32] = a1[r];
    pr[64] = a2[r];
    pr[96] = a3[r];
  }
  rsq += __shfl_xor(rsq, 32, 64);
  if (l < 32) rsL[sq][l31] = rsq;
  __syncthreads();

  {
    const int q = tid >> 3, dg = tid & 7;
    f32x4 os0={0.f,0.f,0.f,0.f}, os1=os0, os2=os0, os3=os0;
    #pragma unroll
    for (int w2=0; w2<4; ++w2){
      const float* pb = Part + (size_t)(w2*32 + q)*132 + dg*16;
      os0 += *(const f32x4*)(pb+0);
      os1 += *(const f32x4*)(pb+4);
      os2 += *(const f32x4*)(pb+8);
      os3 += *(const f32x4*)(pb+12);
    }
    const float rstot = rsL[0][q]+rsL[1][q]+rsL[2][q]+rsL[3][q];
    const int tq = t0 + q;
    const float en = __expf(-(csb[hS+tq] + Mxb[hS+tq]));
    const float iv = 1.f/(fmaxf(fabsf(rstot), en) + 1e-6f);
    f32x4 h0, h1, h2, h3;
    h0[0]=os0[0]*iv; h0[1]=os0[1]*iv; h0[2]=os0[2]*iv; h0[3]=os0[3]*iv;
    h1[0]=os1[0]*iv; h1[1]=os1[1]*iv; h1[2]=os1[2]*iv; h1[3]=os1[3]*iv;
    h2[0]=os2[0]*iv; h2[1]=os2[1]*iv; h2[2]=os2[2]*iv; h2[3]=os2[3]*iv;
    h3[0]=os3[0]*iv; h3[1]=os3[1]*iv; h3[2]=os3[2]*iv; h3[3]=os3[3]*iv;
    float s1 = (h0[0]+h0[1]+h0[2]+h0[3]) + (h1[0]+h1[1]+h1[2]+h1[3])
             + (h2[0]+h2[1]+h2[2]+h2[3]) + (h3[0]+h3[1]+h3[2]+h3[3]);
    float s2 = (h0[0]*h0[0]+h0[1]*h0[1]+h0[2]*h0[2]+h0[3]*h0[3])
             + (h1[0]*h1[0]+h1[1]*h1[1]+h1[2]*h1[2]+h1[3]*h1[3])
             + (h2[0]*h2[0]+h2[1]*h2[1]+h2[2]*h2[2]+h2[3]*h2[3])
             + (h3[0]*h3[0]+h3[1]*h3[1]+h3[2]*h3[2]+h3[3]*h3[3]);
    s1 += __shfl_xor(s1, 1, 64);  s2 += __shfl_xor(s2, 1, 64);
    s1 += __shfl_xor(s1, 2, 64);  s2 += __shfl_xor(s2, 2, 64);
    s1 += __shfl_xor(s1, 4, 64);  s2 += __shfl_xor(s2, 4, 64);
    const float mean = s1*(1.f/128.f);
    const float var  = s2*(1.f/128.f) - mean*mean;
    const float rstd = rsqrtf(var + 1e-5f);
    const float* nb = nw + h*DH + dg*16;
    const f32x4 n0 = *(const f32x4*)(nb+0);
    const f32x4 n1 = *(const f32x4*)(nb+4);
    const f32x4 n2 = *(const f32x4*)(nb+8);
    const f32x4 n3 = *(const f32x4*)(nb+12);
    float* ob = out + (size_t)tq*E_DIM + h*DH + dg*16;
    f32x4 o0v, o1v, o2v, o3v;
    o0v[0]=(h0[0]-mean)*rstd*n0[0]; o0v[1]=(h0[1]-mean)*rstd*n0[1];
    o0v[2]=(h0[2]-mean)*rstd*n0[2]; o0v[3]=(h0[3]-mean)*rstd*n0[3];
    o1v[0]=(h1[0]-mean)*rstd*n1[0]; o1v[1]=(h1[1]-mean)*rstd*n1[1];
    o1v[2]=(h1[2]-mean)*rstd*n1[2]; o1v[3]=(h1[3]-mean)*rstd*n1[3];
    o2v[0]=(h2[0]-mean)*rstd*n2[0]; o2v[1]=(h2[1]-mean)*rstd*n2[1];
    o2v[2]=(h2[2]-mean)*rstd*n2[2]; o2v[3]=(h2[3]-mean)*rstd*n2[3];
    o3v[0]=(h3[0]-mean)*rstd*n3[0]; o3v[1]=(h3[1]-mean)*rstd*n3[1];
    o3v[2]=(h3[2]-mean)*rstd*n3[2]; o3v[3]=(h3[3]-mean)*rstd*n3[3];
    *(f32x4*)(ob+0)  = o0v;
    *(f32x4*)(ob+4)  = o1v;
    *(f32x4*)(ob+8)  = o2v;
    *(f32x4*)(ob+12) = o3v;
  }
}

extern "C" void kernel_launch(void* const* d_in, const int* in_sizes, int n_in,
                              void* d_out, int out_size, void* d_ws, size_t ws_size,
                              hipStream_t stream) {
  const float* q   = (const float*)d_in[0];
  const float* k   = (const float*)d_in[1];
  const float* v   = (const float*)d_in[2];
  const float* igw = (const float*)d_in[3];
  const float* igb = (const float*)d_in[4];
  const float* fgw = (const float*)d_in[5];
  const float* fgb = (const float*)d_in[6];
  const float* nw  = (const float*)d_in[7];
  float* outp = (float*)d_out;

  float* ws  = (float*)d_ws;
  float* ig  = ws;                 // NH*S
  float* lsf = ws + 1*NHEAD*S_LEN;
  float* csb = ws + 2*NHEAD*S_LEN;
  float* Mb  = ws + 3*NHEAD*S_LEN;
  float* mbf = ws + 4*NHEAD*S_LEN;
  ushort* qbb = (ushort*)(ws + 5*NHEAD*S_LEN);          // S*E bf16 (scaled)
  ushort* kbb = qbb + (size_t)S_LEN*E_DIM;              // S*E bf16
  ushort* vtb = kbb + (size_t)S_LEN*E_DIM;              // E*S bf16 (per-head V^T)

  gates_qk<<<S_LEN/4, 256, 0, stream>>>(q, k, v, igw, igb, fgw, fgb,
                                        ig, lsf, qbb, kbb, vtb);
  scan_kernel<<<NHEAD, 256, 0, stream>>>(ig, lsf, csb, Mb, mbf);
  mlstm_mfma6<<<dim3(NHEAD, 64), 256, 0, stream>>>(qbb, kbb, vtb, csb, Mb, mbf, nw, outp);
}

// Round 15
// 61.390 us; speedup vs baseline: 1.2319x; 1.0922x over previous
//
#include <hip/hip_runtime.h>
#include <hip/hip_bf16.h>
#include <math.h>

#define S_LEN 2048
#define E_DIM 1024
#define NHEAD 8
#define DH 128
#define E3 3072

typedef short bf16x8 __attribute__((ext_vector_type(8)));
typedef short bf16x4 __attribute__((ext_vector_type(4)));
typedef float f32x4 __attribute__((ext_vector_type(4)));
typedef float f32x16 __attribute__((ext_vector_type(16)));

#define MFMA3216(a,b,c) __builtin_amdgcn_mfma_f32_32x32x16_bf16(a,b,c,0,0,0)
#define Z16 {0.f,0.f,0.f,0.f,0.f,0.f,0.f,0.f,0.f,0.f,0.f,0.f,0.f,0.f,0.f,0.f}
#define CROW(r) (((r)&3) + 8*((r)>>2))

__device__ __forceinline__ unsigned short f2bf(float f){
  union{float f; unsigned u;} x; x.f = f;
  unsigned r = x.u + 0x7FFF + ((x.u>>16)&1);
  return (unsigned short)(r>>16);
}

__device__ __forceinline__ unsigned cvtpk(float lo, float hi){
  unsigned r;
  asm("v_cvt_pk_bf16_f32 %0, %1, %2" : "=v"(r) : "v"(lo), "v"(hi));
  return r;
}

__device__ __forceinline__ float logsigf(float x){
  return fminf(x, 0.f) - log1pf(expf(-fabsf(x)));
}

typedef const __attribute__((address_space(1))) unsigned int* gas1_t;
typedef __attribute__((address_space(3))) unsigned int* las3_t;
__device__ __forceinline__ void stage16(const ushort* g, ushort* l){
  __builtin_amdgcn_global_load_lds((gas1_t)(const void*)g, (las3_t)(void*)l, 16, 0, 0);
}

// ------ Kernel A: r9's proven gates (acc[64] butterfly) + fused V^T --------
// 4 t-rows/block, inputs read ONCE per block (shared across all 16 gate rows
// via acc[64]). step==2 additionally emits the transposed V^T bf16 (each
// thread owns d = tid*4..+3 for the block's 4 t-rows) -> vtrans kernel gone.
__global__ __launch_bounds__(256) void gates_qk(
    const float* __restrict__ q, const float* __restrict__ k, const float* __restrict__ v,
    const float* __restrict__ igw, const float* __restrict__ igb,
    const float* __restrict__ fgw, const float* __restrict__ fgb,
    float* __restrict__ ig_out, float* __restrict__ lsf_out,
    ushort* __restrict__ qbo, ushort* __restrict__ kbo, ushort* __restrict__ vto){
  const int t0 = blockIdx.x*4;
  const int tid = threadIdx.x;
  const int lane = tid & 63, wv = tid >> 6;
  float acc[64];
  #pragma unroll
  for (int a=0;a<64;++a) acc[a]=0.f;
  const float sc = 0.08838834764831845f;  // 1/sqrt(128)
  #pragma unroll
  for (int step=0; step<3; ++step){
    const float* src = (step==0)? q : ((step==1)? k : v);
    float4 in4[4];
    #pragma unroll
    for (int r=0;r<4;++r) in4[r] = ((const float4*)src)[(size_t)(t0+r)*256 + tid];
    if (step==0){
      #pragma unroll
      for (int r=0;r<4;++r){
        ushort4 o; o.x=f2bf(in4[r].x*sc); o.y=f2bf(in4[r].y*sc);
        o.z=f2bf(in4[r].z*sc); o.w=f2bf(in4[r].w*sc);
        ((ushort4*)qbo)[(size_t)(t0+r)*256 + tid] = o;
      }
    } else if (step==1){
      #pragma unroll
      for (int r=0;r<4;++r){
        ushort4 o; o.x=f2bf(in4[r].x); o.y=f2bf(in4[r].y);
        o.z=f2bf(in4[r].z); o.w=f2bf(in4[r].w);
        ((ushort4*)kbo)[(size_t)(t0+r)*256 + tid] = o;
      }
    } else {
      // fused V^T: d = tid*4+c (global over E == h*DH+dloc), 4 t-rows -> 8B
      #pragma unroll
      for (int c=0;c<4;++c){
        ushort4 ov;
        ov.x = f2bf(((const float*)&in4[0])[c]);
        ov.y = f2bf(((const float*)&in4[1])[c]);
        ov.z = f2bf(((const float*)&in4[2])[c]);
        ov.w = f2bf(((const float*)&in4[3])[c]);
        *(ushort4*)(vto + (size_t)(tid*4+c)*S_LEN + t0) = ov;
      }
    }
    const int wj = step*256 + tid;
    #pragma unroll
    for (int o=0;o<8;++o){
      float4 wI = ((const float4*)igw)[o*768 + wj];
      float4 wF = ((const float4*)fgw)[o*768 + wj];
      #pragma unroll
      for (int r=0;r<4;++r){
        acc[o*4+r]    = fmaf(in4[r].x, wI.x, acc[o*4+r]);
        acc[o*4+r]    = fmaf(in4[r].y, wI.y, acc[o*4+r]);
        acc[o*4+r]    = fmaf(in4[r].z, wI.z, acc[o*4+r]);
        acc[o*4+r]    = fmaf(in4[r].w, wI.w, acc[o*4+r]);
        acc[32+o*4+r] = fmaf(in4[r].x, wF.x, acc[32+o*4+r]);
        acc[32+o*4+r] = fmaf(in4[r].y, wF.y, acc[32+o*4+r]);
        acc[32+o*4+r] = fmaf(in4[r].z, wF.z, acc[32+o*4+r]);
        acc[32+o*4+r] = fmaf(in4[r].w, wF.w, acc[32+o*4+r]);
      }
    }
  }
  int cnt = 32;
  #pragma unroll
  for (int s=0; s<6; ++s){
    const bool hib = (lane >> s) & 1;
    #pragma unroll
    for (int a=0; a<32; ++a){
      if (a < cnt){
        float sent = hib ? acc[a] : acc[a+cnt];
        float got = __shfl_xor(sent, 1<<s, 64);
        acc[a] = (hib ? acc[a+cnt] : acc[a]) + got;
      }
    }
    cnt >>= 1;
  }
  __shared__ float red[4][64];
  red[wv][lane] = acc[0];
  __syncthreads();
  if (tid < 64){
    float tot = red[0][tid]+red[1][tid]+red[2][tid]+red[3][tid];
    int a = (int)(__brev((unsigned)tid) >> 26);   // bitrev6
    int f = a >> 5, o = (a>>2)&7, r = a&3;
    int t = t0 + r;
    if (f==0) ig_out[o*S_LEN + t] = tot + igb[o];
    else      lsf_out[o*S_LEN + t] = logsigf(tot + fgb[o]);
  }
}

// ---------------- Kernel B: per-head scans ---------------------------------
__global__ __launch_bounds__(256) void scan_kernel(
    const float* __restrict__ ig, const float* __restrict__ lsf,
    float* __restrict__ cs_out, float* __restrict__ M_out, float* __restrict__ m_out){
  const int h = blockIdx.x;
  const int tid = threadIdx.x;
  __shared__ float tt[256];
  const int base = tid*8;
  const float* src = lsf + h*S_LEN;
  float loc[8]; float tot = 0.f;
  #pragma unroll
  for (int i=0;i<8;++i){ tot += src[base+i]; loc[i]=tot; }
  tt[tid]=tot; __syncthreads();
  for (int off=1; off<256; off<<=1){
    float add = (tid>=off)? tt[tid-off] : 0.f;
    __syncthreads();
    tt[tid] += add;
    __syncthreads();
  }
  const float excl = tt[tid] - tot;
  float csv[8];
  #pragma unroll
  for (int i=0;i<8;++i){ csv[i] = excl + loc[i]; cs_out[h*S_LEN+base+i]=csv[i]; }
  const float* igp = ig + h*S_LEN;
  float mloc[8], mval[8]; float mtot = -INFINITY;
  #pragma unroll
  for (int i=0;i<8;++i){
    float m = igp[base+i] - csv[i];
    mval[i] = m;
    mtot = fmaxf(mtot, m);
    mloc[i] = mtot;
  }
  __syncthreads();
  tt[tid]=mtot; __syncthreads();
  for (int off=1; off<256; off<<=1){
    float add = (tid>=off)? tt[tid-off] : -INFINITY;
    __syncthreads();
    tt[tid] = fmaxf(tt[tid], add);
    __syncthreads();
  }
  const float exclm = (tid>0)? tt[tid-1] : -INFINITY;
  #pragma unroll
  for (int i=0;i<8;++i){
    M_out[h*S_LEN+base+i] = fmaxf(exclm, mloc[i]);
    m_out[h*S_LEN+base+i] = mval[i];
  }
}

// ---------------- Kernel C: r9 measured-best structure (unchanged) ---------
__global__ __launch_bounds__(256, 2) void mlstm_mfma6(
    const ushort* __restrict__ qb, const ushort* __restrict__ kb,
    const ushort* __restrict__ vt,
    const float* __restrict__ csb, const float* __restrict__ Mxb,
    const float* __restrict__ mbb,
    const float* __restrict__ nw, float* __restrict__ out){
  const int h = blockIdx.x;
  const int qt = 63 - blockIdx.y;            // LPT: biggest q-tile first
  const int tid = threadIdx.x, l = tid & 63;
  const int sq = tid >> 6;                   // wave = s-quarter 0..3
  const int l31 = l & 31, l15 = l & 15, hi = l >> 5;

  __shared__ __align__(16) float UNI[4*32*132];   // 67584 B union
  __shared__ float MB[128];
  __shared__ float rsL[4][32];
  ushort* Kb = (ushort*)UNI;                 // 32 KB: [128 s][16 chunks]
  ushort* Vb = Kb + 16384;                   // 32 KB: [128 d][16 chunks]
  float*  Part = UNI;                        // [4 w][32 q][132]

  const int hS = h*S_LEN;
  const ushort* kbh = kb + h*DH;
  const ushort* vth = vt + (size_t)h*DH*S_LEN;
  const float*  mh  = mbb + hS;
  const int t0 = qt*32;
  const int NT = (t0 + 31)/128 + 1;
  const int tgq = t0 + l31;
  const float Mq = Mxb[hS + tgq];

  bf16x8 qf0,qf1,qf2,qf3,qf4,qf5,qf6,qf7;
  { const ushort* qs = qb + (size_t)tgq*E_DIM + h*DH + hi*8;
    qf0 = *(const bf16x8*)(qs+0);   qf1 = *(const bf16x8*)(qs+16);
    qf2 = *(const bf16x8*)(qs+32);  qf3 = *(const bf16x8*)(qs+48);
    qf4 = *(const bf16x8*)(qs+64);  qf5 = *(const bf16x8*)(qs+80);
    qf6 = *(const bf16x8*)(qs+96);  qf7 = *(const bf16x8*)(qs+112); }

  f32x16 a0 = Z16, a1 = Z16, a2 = Z16, a3 = Z16;
  float rsq = 0.f;

#define STAGE6(ktv) {                                                        \
    _Pragma("unroll")                                                        \
    for (int i_=0;i_<8;++i_){                                                \
      const int L_ = tid + i_*256; const int row_ = L_>>4, pc_ = L_&15;      \
      stage16(kbh + (size_t)((ktv)*128+row_)*E_DIM + ((pc_^(row_&15))<<3),   \
              Kb + (size_t)L_*8); }                                          \
    _Pragma("unroll")                                                        \
    for (int i_=0;i_<8;++i_){                                                \
      const int L_ = tid + i_*256; const int d_ = L_>>4, pc_ = L_&15;        \
      stage16(vth + (size_t)d_*S_LEN + (ktv)*128 + ((pc_^(d_&15))<<3),       \
              Vb + (size_t)L_*8); }                                          \
    if (tid < 32)                                                            \
      stage16((const ushort*)(mh + (ktv)*128) + tid*8,                       \
              (ushort*)MB + tid*8); }

#define LV6(dt, cs) (*(const bf16x8*)(Vb + (size_t)((dt)*32+l31)*128 + (((cs)^l15)<<3)))

  for (int kt=0; kt<NT; ++kt){
    if (kt) __syncthreads();                 // prev tile's LDS readers done
    STAGE6(kt);
    __syncthreads();                         // stage landed (vmcnt drained)

    const ushort* kbase = Kb + (size_t)(sq*32 + l31)*128;
    f32x16 cc = Z16;
    { bf16x8 ka;
      ka = *(const bf16x8*)(kbase + (((0*2+hi)^l15)<<3)); cc = MFMA3216(ka, qf0, cc);
      ka = *(const bf16x8*)(kbase + (((1*2+hi)^l15)<<3)); cc = MFMA3216(ka, qf1, cc);
      ka = *(const bf16x8*)(kbase + (((2*2+hi)^l15)<<3)); cc = MFMA3216(ka, qf2, cc);
      ka = *(const bf16x8*)(kbase + (((3*2+hi)^l15)<<3)); cc = MFMA3216(ka, qf3, cc);
      ka = *(const bf16x8*)(kbase + (((4*2+hi)^l15)<<3)); cc = MFMA3216(ka, qf4, cc);
      ka = *(const bf16x8*)(kbase + (((5*2+hi)^l15)<<3)); cc = MFMA3216(ka, qf5, cc);
      ka = *(const bf16x8*)(kbase + (((6*2+hi)^l15)<<3)); cc = MFMA3216(ka, qf6, cc);
      ka = *(const bf16x8*)(kbase + (((7*2+hi)^l15)<<3)); cc = MFMA3216(ka, qf7, cc); }

    bf16x8 fE, fO;
    {
      const int sb_ = kt*128 + sq*32 + 4*hi;
      const f32x4 mA_ = *(const f32x4*)&MB[sq*32 +  0 + 4*hi];
      const f32x4 mB_ = *(const f32x4*)&MB[sq*32 +  8 + 4*hi];
      const f32x4 mC_ = *(const f32x4*)&MB[sq*32 + 16 + 4*hi];
      const f32x4 mD_ = *(const f32x4*)&MB[sq*32 + 24 + 4*hi];
      float p0  = (sb_+0  <= tgq) ? cc[0] *__expf(mA_[0]-Mq) : 0.f;
      float p1  = (sb_+1  <= tgq) ? cc[1] *__expf(mA_[1]-Mq) : 0.f;
      float p2  = (sb_+2  <= tgq) ? cc[2] *__expf(mA_[2]-Mq) : 0.f;
      float p3  = (sb_+3  <= tgq) ? cc[3] *__expf(mA_[3]-Mq) : 0.f;
      float p4  = (sb_+8  <= tgq) ? cc[4] *__expf(mB_[0]-Mq) : 0.f;
      float p5  = (sb_+9  <= tgq) ? cc[5] *__expf(mB_[1]-Mq) : 0.f;
      float p6  = (sb_+10 <= tgq) ? cc[6] *__expf(mB_[2]-Mq) : 0.f;
      float p7  = (sb_+11 <= tgq) ? cc[7] *__expf(mB_[3]-Mq) : 0.f;
      float p8  = (sb_+16 <= tgq) ? cc[8] *__expf(mC_[0]-Mq) : 0.f;
      float p9  = (sb_+17 <= tgq) ? cc[9] *__expf(mC_[1]-Mq) : 0.f;
      float p10 = (sb_+18 <= tgq) ? cc[10]*__expf(mC_[2]-Mq) : 0.f;
      float p11 = (sb_+19 <= tgq) ? cc[11]*__expf(mC_[3]-Mq) : 0.f;
      float p12 = (sb_+24 <= tgq) ? cc[12]*__expf(mD_[0]-Mq) : 0.f;
      float p13 = (sb_+25 <= tgq) ? cc[13]*__expf(mD_[1]-Mq) : 0.f;
      float p14 = (sb_+26 <= tgq) ? cc[14]*__expf(mD_[2]-Mq) : 0.f;
      float p15 = (sb_+27 <= tgq) ? cc[15]*__expf(mD_[3]-Mq) : 0.f;
      rsq += ((p0+p1)+(p2+p3))+((p4+p5)+(p6+p7))
           + ((p8+p9)+(p10+p11))+((p12+p13)+(p14+p15));
      unsigned A0_=cvtpk(p0,p1),  A1_=cvtpk(p2,p3);
      unsigned B0_=cvtpk(p4,p5),  B1_=cvtpk(p6,p7);
      unsigned C0_=cvtpk(p8,p9),  C1_=cvtpk(p10,p11);
      unsigned D0_=cvtpk(p12,p13),D1_=cvtpk(p14,p15);
      unsigned A0x_=(unsigned)__shfl_xor((int)A0_,32,64);
      unsigned B0x_=(unsigned)__shfl_xor((int)B0_,32,64);
      unsigned A1x_=(unsigned)__shfl_xor((int)A1_,32,64);
      unsigned B1x_=(unsigned)__shfl_xor((int)B1_,32,64);
      unsigned C0x_=(unsigned)__shfl_xor((int)C0_,32,64);
      unsigned D0x_=(unsigned)__shfl_xor((int)D0_,32,64);
      unsigned C1x_=(unsigned)__shfl_xor((int)C1_,32,64);
      unsigned D1x_=(unsigned)__shfl_xor((int)D1_,32,64);
      { unsigned* u_ = (unsigned*)&fE;
        u_[0] = hi ? B0x_ : A0_;  u_[1] = hi ? B1x_ : A1_;
        u_[2] = hi ? B0_  : A0x_; u_[3] = hi ? B1_  : A1x_; }
      { unsigned* u_ = (unsigned*)&fO;
        u_[0] = hi ? D0x_ : C0_;  u_[1] = hi ? D1x_ : C1_;
        u_[2] = hi ? D0_  : C0x_; u_[3] = hi ? D1_  : C1x_; }
    }

    a0 = MFMA3216(fE, LV6(0, sq*4 + 0 + hi), a0);
    a1 = MFMA3216(fE, LV6(1, sq*4 + 0 + hi), a1);
    a2 = MFMA3216(fE, LV6(2, sq*4 + 0 + hi), a2);
    a3 = MFMA3216(fE, LV6(3, sq*4 + 0 + hi), a3);
    a0 = MFMA3216(fO, LV6(0, sq*4 + 2 + hi), a0);
    a1 = MFMA3216(fO, LV6(1, sq*4 + 2 + hi), a1);
    a2 = MFMA3216(fO, LV6(2, sq*4 + 2 + hi), a2);
    a3 = MFMA3216(fO, LV6(3, sq*4 + 2 + hi), a3);
  }

  // -------- epilogue: cross-wave reduce (LDS union) + normalizer + LN ------
  __syncthreads();
  #pragma unroll
  for (int r=0;r<16;++r){
    const int qrow = CROW(r) + 4*hi;
    float* pr = Part + (size_t)(sq*32 + qrow)*132 + l31;
    pr[0]  = a0[r];
    pr[32] = a1[r];
    pr[64] = a2[r];
    pr[96] = a3[r];
  }
  rsq += __shfl_xor(rsq, 32, 64);
  if (l < 32) rsL[sq][l31] = rsq;
  __syncthreads();

  {
    const int q = tid >> 3, dg = tid & 7;
    f32x4 os0={0.f,0.f,0.f,0.f}, os1=os0, os2=os0, os3=os0;
    #pragma unroll
    for (int w2=0; w2<4; ++w2){
      const float* pb = Part + (size_t)(w2*32 + q)*132 + dg*16;
      os0 += *(const f32x4*)(pb+0);
      os1 += *(const f32x4*)(pb+4);
      os2 += *(const f32x4*)(pb+8);
      os3 += *(const f32x4*)(pb+12);
    }
    const float rstot = rsL[0][q]+rsL[1][q]+rsL[2][q]+rsL[3][q];
    const int tq = t0 + q;
    const float en = __expf(-(csb[hS+tq] + Mxb[hS+tq]));
    const float iv = 1.f/(fmaxf(fabsf(rstot), en) + 1e-6f);
    f32x4 h0, h1, h2, h3;
    h0[0]=os0[0]*iv; h0[1]=os0[1]*iv; h0[2]=os0[2]*iv; h0[3]=os0[3]*iv;
    h1[0]=os1[0]*iv; h1[1]=os1[1]*iv; h1[2]=os1[2]*iv; h1[3]=os1[3]*iv;
    h2[0]=os2[0]*iv; h2[1]=os2[1]*iv; h2[2]=os2[2]*iv; h2[3]=os2[3]*iv;
    h3[0]=os3[0]*iv; h3[1]=os3[1]*iv; h3[2]=os3[2]*iv; h3[3]=os3[3]*iv;
    float s1 = (h0[0]+h0[1]+h0[2]+h0[3]) + (h1[0]+h1[1]+h1[2]+h1[3])
             + (h2[0]+h2[1]+h2[2]+h2[3]) + (h3[0]+h3[1]+h3[2]+h3[3]);
    float s2 = (h0[0]*h0[0]+h0[1]*h0[1]+h0[2]*h0[2]+h0[3]*h0[3])
             + (h1[0]*h1[0]+h1[1]*h1[1]+h1[2]*h1[2]+h1[3]*h1[3])
             + (h2[0]*h2[0]+h2[1]*h2[1]+h2[2]*h2[2]+h2[3]*h2[3])
             + (h3[0]*h3[0]+h3[1]*h3[1]+h3[2]*h3[2]+h3[3]*h3[3]);
    s1 += __shfl_xor(s1, 1, 64);  s2 += __shfl_xor(s2, 1, 64);
    s1 += __shfl_xor(s1, 2, 64);  s2 += __shfl_xor(s2, 2, 64);
    s1 += __shfl_xor(s1, 4, 64);  s2 += __shfl_xor(s2, 4, 64);
    const float mean = s1*(1.f/128.f);
    const float var  = s2*(1.f/128.f) - mean*mean;
    const float rstd = rsqrtf(var + 1e-5f);
    const float* nb = nw + h*DH + dg*16;
    const f32x4 n0 = *(const f32x4*)(nb+0);
    const f32x4 n1 = *(const f32x4*)(nb+4);
    const f32x4 n2 = *(const f32x4*)(nb+8);
    const f32x4 n3 = *(const f32x4*)(nb+12);
    float* ob = out + (size_t)tq*E_DIM + h*DH + dg*16;
    f32x4 o0v, o1v, o2v, o3v;
    o0v[0]=(h0[0]-mean)*rstd*n0[0]; o0v[1]=(h0[1]-mean)*rstd*n0[1];
    o0v[2]=(h0[2]-mean)*rstd*n0[2]; o0v[3]=(h0[3]-mean)*rstd*n0[3];
    o1v[0]=(h1[0]-mean)*rstd*n1[0]; o1v[1]=(h1[1]-mean)*rstd*n1[1];
    o1v[2]=(h1[2]-mean)*rstd*n1[2]; o1v[3]=(h1[3]-mean)*rstd*n1[3];
    o2v[0]=(h2[0]-mean)*rstd*n2[0]; o2v[1]=(h2[1]-mean)*rstd*n2[1];
    o2v[2]=(h2[2]-mean)*rstd*n2[2]; o2v[3]=(h2[3]-mean)*rstd*n2[3];
    o3v[0]=(h3[0]-mean)*rstd*n3[0]; o3v[1]=(h3[1]-mean)*rstd*n3[1];
    o3v[2]=(h3[2]-mean)*rstd*n3[2]; o3v[3]=(h3[3]-mean)*rstd*n3[3];
    *(f32x4*)(ob+0)  = o0v;
    *(f32x4*)(ob+4)  = o1v;
    *(f32x4*)(ob+8)  = o2v;
    *(f32x4*)(ob+12) = o3v;
  }
}

extern "C" void kernel_launch(void* const* d_in, const int* in_sizes, int n_in,
                              void* d_out, int out_size, void* d_ws, size_t ws_size,
                              hipStream_t stream) {
  const float* q   = (const float*)d_in[0];
  const float* k   = (const float*)d_in[1];
  const float* v   = (const float*)d_in[2];
  const float* igw = (const float*)d_in[3];
  const float* igb = (const float*)d_in[4];
  const float* fgw = (const float*)d_in[5];
  const float* fgb = (const float*)d_in[6];
  const float* nw  = (const float*)d_in[7];
  float* outp = (float*)d_out;

  float* ws  = (float*)d_ws;
  float* ig  = ws;                 // NH*S
  float* lsf = ws + 1*NHEAD*S_LEN;
  float* csb = ws + 2*NHEAD*S_LEN;
  float* Mb  = ws + 3*NHEAD*S_LEN;
  float* mbf = ws + 4*NHEAD*S_LEN;
  ushort* qbb = (ushort*)(ws + 5*NHEAD*S_LEN);          // S*E bf16 (scaled)
  ushort* kbb = qbb + (size_t)S_LEN*E_DIM;              // S*E bf16
  ushort* vtb = kbb + (size_t)S_LEN*E_DIM;              // E*S bf16 (per-head V^T)

  gates_qk<<<S_LEN/4, 256, 0, stream>>>(q, k, v, igw, igb, fgw, fgb,
                                        ig, lsf, qbb, kbb, vtb);
  scan_kernel<<<NHEAD, 256, 0, stream>>>(ig, lsf, csb, Mb, mbf);
  mlstm_mfma6<<<dim3(NHEAD, 64), 256, 0, stream>>>(qbb, kbb, vtb, csb, Mb, mbf, nw, outp);
}